// Round 1
// baseline (668.231 us; speedup 1.0000x reference)
//
#include <hip/hip_runtime.h>
#include <hip/hip_bf16.h>

typedef short short8 __attribute__((ext_vector_type(8)));
typedef float floatx4 __attribute__((ext_vector_type(4)));

#define XP 328   // X LDS pitch (bf16 elems): 656 B, 16B-aligned rows, 2-way bank aliasing only
#define HP 168   // H LDS pitch: 336 B, 16B-aligned rows

__device__ __forceinline__ unsigned short f2bf(float f) {
    __hip_bfloat16 h = __float2bfloat16(f);
    return __builtin_bit_cast(unsigned short, h);
}
__device__ __forceinline__ float bf2f(unsigned short s) {
    __hip_bfloat16 h = __builtin_bit_cast(__hip_bfloat16, s);
    return __bfloat162float(h);
}

// Pack Wc = [w1; wt] (320 out x 320 in) into B-fragment order for mfma_f32_16x16x32_bf16.
// Frag (t = n-tile of 16, kb = k-block of 32): elem j of lane l is B[k][n],
// n = t*16 + (l&15), k = kb*32 + (l>>4)*8 + j. Stored flat: (((t*10+kb)*64+l)*8+j).
__global__ void pack_wc(const float* __restrict__ w1, const float* __restrict__ wt,
                        unsigned short* __restrict__ dst) {
    int i = blockIdx.x * 256 + threadIdx.x;
    if (i >= 320 * 320) return;
    int j = i & 7;
    int lane = (i >> 3) & 63;
    int r = i >> 9;
    int kb = r % 10;
    int t = r / 10;
    int n = t * 16 + (lane & 15);
    int k = kb * 32 + ((lane >> 4) << 3) + j;
    float v = (n < 160) ? w1[n * 320 + k] : wt[(n - 160) * 320 + k];
    dst[i] = f2bf(v);
}

__global__ void pack_w2(const float* __restrict__ w2, unsigned short* __restrict__ dst) {
    int i = blockIdx.x * 256 + threadIdx.x;
    if (i >= 160 * 160) return;
    int j = i & 7;
    int lane = (i >> 3) & 63;
    int r = i >> 9;
    int kb = r % 5;
    int t = r / 5;
    int n = t * 16 + (lane & 15);
    int k = kb * 32 + ((lane >> 4) << 3) + j;
    dst[i] = f2bf(w2[n * 160 + k]);
}

// Fused: gather+concat -> GEMM1(320x320) -> GN1+ReLU -> GEMM2(160x160) -> GN2 + skip + ReLU -> head dot
__global__ __launch_bounds__(256, 3) void fused_kernel(
    const float* __restrict__ actors, const float* __restrict__ paths,
    const float* __restrict__ Z_act, const float* __restrict__ Z_pat,
    const int* __restrict__ u,
    const unsigned short* __restrict__ pB1, const unsigned short* __restrict__ pB2,
    const float* __restrict__ g1w, const float* __restrict__ g1b,
    const float* __restrict__ g2w, const float* __restrict__ g2b,
    const float* __restrict__ wh, const float* __restrict__ bh,
    float* __restrict__ out)
{
    // LDS: region [0,41984) = X tile (64 x XP bf16); after GEMM1 it is dead and
    // re-used: [0,21504) = h1/h2 (64 x HP bf16), [21504,43008) = ht. Stats at 43008.
    __shared__ __align__(16) char smem[45056];
    unsigned short* lX  = (unsigned short*)smem;
    unsigned short* lH1 = (unsigned short*)smem;
    unsigned short* lHT = (unsigned short*)(smem + 21504);
    float* sSum = (float*)(smem + 43008);  // [4][64]
    float* sSsq = sSum + 256;              // [4][64]

    const int tid  = threadIdx.x;
    const int wave = tid >> 6;
    const int lane = tid & 63;
    const int quad = lane >> 4;
    const int l15  = lane & 15;
    const int row0 = blockIdx.x * 64;

    // ---- stage X = [paths | Z_pat | actors[u] | Z_act[u]] as bf16 into LDS ----
    for (int f = tid; f < 64 * 80; f += 256) {
        int r = f / 80;
        int q = f - r * 80;           // float4 index within the 320-ch row
        int n = row0 + r;
        float4 v;
        if (q < 32) {
            v = ((const float4*)(paths + (size_t)n * 128))[q];
        } else if (q < 40) {
            v = ((const float4*)(Z_pat + (size_t)n * 32))[q - 32];
        } else {
            int un = u[n];
            if (q < 72) v = ((const float4*)(actors + (size_t)un * 128))[q - 40];
            else        v = ((const float4*)(Z_act + (size_t)un * 32))[q - 72];
        }
        ushort4 sv;
        sv.x = f2bf(v.x); sv.y = f2bf(v.y); sv.z = f2bf(v.z); sv.w = f2bf(v.w);
        *(ushort4*)(lX + r * XP + q * 4) = sv;
    }
    __syncthreads();

    // ---- GEMM1: C[64 x 320] = X @ [w1;wt]^T ; wave handles output cols [80*wave, 80*wave+80) ----
    floatx4 fzero = {0.f, 0.f, 0.f, 0.f};
    floatx4 acc[4][5];
    #pragma unroll
    for (int i = 0; i < 4; i++)
        #pragma unroll
        for (int j = 0; j < 5; j++) acc[i][j] = fzero;

    for (int kb = 0; kb < 10; kb++) {
        short8 a[4];
        #pragma unroll
        for (int mt = 0; mt < 4; mt++)
            a[mt] = *(const short8*)(lX + (mt * 16 + l15) * XP + kb * 32 + quad * 8);
        #pragma unroll
        for (int ti = 0; ti < 5; ti++) {
            int t = wave * 5 + ti;
            short8 b = *(const short8*)(pB1 + ((size_t)(t * 10 + kb) * 64 + lane) * 8);
            #pragma unroll
            for (int mt = 0; mt < 4; mt++)
                acc[mt][ti] = __builtin_amdgcn_mfma_f32_16x16x32_bf16(a[mt], b, acc[mt][ti], 0, 0, 0);
        }
    }
    __syncthreads();  // all X reads complete; LDS region can be overwritten

    // ---- writeback: cols<160 -> h1_pre, cols>=160 -> ht (bf16) ----
    #pragma unroll
    for (int ti = 0; ti < 5; ti++) {
        int n = wave * 80 + ti * 16 + l15;   // wave-uniform branch below
        unsigned short* dstbase = (n < 160) ? (lH1 + n) : (lHT + (n - 160));
        #pragma unroll
        for (int mt = 0; mt < 4; mt++) {
            #pragma unroll
            for (int r = 0; r < 4; r++) {
                int m = mt * 16 + quad * 4 + r;
                dstbase[m * HP] = f2bf(acc[mt][ti][r]);
            }
        }
    }
    __syncthreads();

    // ---- GN1 + ReLU (in place, 4 threads per row, 40 ch each) ----
    {
        int row = tid >> 2, part = tid & 3;
        int base = row * HP + part * 40;
        float s = 0.f, s2 = 0.f;
        #pragma unroll 8
        for (int c = 0; c < 40; c++) {
            float v = bf2f(lH1[base + c]);
            s += v; s2 += v * v;
        }
        sSum[part * 64 + row] = s;
        sSsq[part * 64 + row] = s2;
        __syncthreads();
        float ts = 0.f, ts2 = 0.f;
        #pragma unroll
        for (int p = 0; p < 4; p++) { ts += sSum[p * 64 + row]; ts2 += sSsq[p * 64 + row]; }
        float mu = ts * (1.f / 160.f);
        float var = ts2 * (1.f / 160.f) - mu * mu;
        float rstd = rsqrtf(var + 1e-5f);
        #pragma unroll 8
        for (int c = 0; c < 40; c++) {
            int ch = part * 40 + c;
            float v = bf2f(lH1[row * HP + ch]);
            v = (v - mu) * rstd * g1w[ch] + g1b[ch];
            v = fmaxf(v, 0.f);
            lH1[row * HP + ch] = f2bf(v);
        }
    }
    __syncthreads();

    // ---- GEMM2: h2[64 x 160] = h1 @ w2^T ; wave (wm = rows half, wn = cols half) ----
    floatx4 acc2[2][5];
    #pragma unroll
    for (int i = 0; i < 2; i++)
        #pragma unroll
        for (int j = 0; j < 5; j++) acc2[i][j] = fzero;
    int wm = wave & 1, wn = wave >> 1;
    for (int kb = 0; kb < 5; kb++) {
        short8 a[2];
        #pragma unroll
        for (int mt = 0; mt < 2; mt++)
            a[mt] = *(const short8*)(lH1 + (wm * 32 + mt * 16 + l15) * HP + kb * 32 + quad * 8);
        #pragma unroll
        for (int ti = 0; ti < 5; ti++) {
            int t = wn * 5 + ti;
            short8 b = *(const short8*)(pB2 + ((size_t)(t * 5 + kb) * 64 + lane) * 8);
            #pragma unroll
            for (int mt = 0; mt < 2; mt++)
                acc2[mt][ti] = __builtin_amdgcn_mfma_f32_16x16x32_bf16(a[mt], b, acc2[mt][ti], 0, 0, 0);
        }
    }
    __syncthreads();  // all h1 reads done; overwrite with h2
    #pragma unroll
    for (int ti = 0; ti < 5; ti++) {
        int n = wn * 80 + ti * 16 + l15;
        #pragma unroll
        for (int mt = 0; mt < 2; mt++) {
            #pragma unroll
            for (int r = 0; r < 4; r++) {
                int m = wm * 32 + mt * 16 + quad * 4 + r;
                lH1[m * HP + n] = f2bf(acc2[mt][ti][r]);
            }
        }
    }
    __syncthreads();

    // ---- GN2 + skip(ht) + ReLU + head dot ----
    {
        int row = tid >> 2, part = tid & 3;
        int base = row * HP + part * 40;
        float s = 0.f, s2 = 0.f;
        #pragma unroll 8
        for (int c = 0; c < 40; c++) {
            float v = bf2f(lH1[base + c]);
            s += v; s2 += v * v;
        }
        sSum[part * 64 + row] = s;
        sSsq[part * 64 + row] = s2;
        __syncthreads();
        float ts = 0.f, ts2 = 0.f;
        #pragma unroll
        for (int p = 0; p < 4; p++) { ts += sSum[p * 64 + row]; ts2 += sSsq[p * 64 + row]; }
        float mu = ts * (1.f / 160.f);
        float var = ts2 * (1.f / 160.f) - mu * mu;
        float rstd = rsqrtf(var + 1e-5f);
        float dp = 0.f;
        #pragma unroll 8
        for (int c = 0; c < 40; c++) {
            int ch = part * 40 + c;
            float v = bf2f(lH1[row * HP + ch]);
            v = (v - mu) * rstd * g2w[ch] + g2b[ch];
            v += bf2f(lHT[row * HP + ch]);
            v = fmaxf(v, 0.f);
            dp += v * wh[ch];
        }
        __syncthreads();   // stats reads done before sSum reuse
        sSum[part * 64 + row] = dp;
        __syncthreads();
        if (part == 0) {
            float o = sSum[row] + sSum[64 + row] + sSum[128 + row] + sSum[192 + row] + bh[0];
            out[row0 + row] = o;
        }
    }
}

extern "C" void kernel_launch(void* const* d_in, const int* in_sizes, int n_in,
                              void* d_out, int out_size, void* d_ws, size_t ws_size,
                              hipStream_t stream) {
    const float* actors = (const float*)d_in[0];
    const float* paths  = (const float*)d_in[1];
    const float* Z_act  = (const float*)d_in[2];
    const float* Z_pat  = (const float*)d_in[3];
    const int*   u      = (const int*)d_in[4];
    const float* w1     = (const float*)d_in[5];
    const float* w2     = (const float*)d_in[6];
    const float* wt     = (const float*)d_in[7];
    const float* g1w    = (const float*)d_in[8];
    const float* g1b    = (const float*)d_in[9];
    const float* g2w    = (const float*)d_in[10];
    const float* g2b    = (const float*)d_in[11];
    const float* wh     = (const float*)d_in[12];
    const float* bh     = (const float*)d_in[13];
    float* out = (float*)d_out;

    unsigned short* pB1 = (unsigned short*)d_ws;          // 320*320 bf16 = 204800 B
    unsigned short* pB2 = pB1 + 320 * 320;                // 160*160 bf16 =  51200 B

    hipLaunchKernelGGL(pack_wc, dim3(400), dim3(256), 0, stream, w1, wt, pB1);
    hipLaunchKernelGGL(pack_w2, dim3(100), dim3(256), 0, stream, w2, pB2);
    hipLaunchKernelGGL(fused_kernel, dim3(400000 / 64), dim3(256), 0, stream,
                       actors, paths, Z_act, Z_pat, u, pB1, pB2,
                       g1w, g1b, g2w, g2b, wh, bh, out);
}

// Round 2
// 500.230 us; speedup vs baseline: 1.3358x; 1.3358x over previous
//
#include <hip/hip_runtime.h>
#include <hip/hip_bf16.h>

typedef short short8 __attribute__((ext_vector_type(8)));
typedef float floatx4 __attribute__((ext_vector_type(4)));

#define XP 328   // X LDS pitch (bf16): 656 B rows; lane-stride 164 words = 4 mod 32 -> 2-way only
#define HP 168   // H LDS pitch: 336 B rows; lane-stride 84 words = 20 mod 32 -> 2-way only

__device__ __forceinline__ unsigned short f2bf(float f) {
    __hip_bfloat16 h = __float2bfloat16(f);
    return __builtin_bit_cast(unsigned short, h);
}
__device__ __forceinline__ float bf2f(unsigned short s) {
    __hip_bfloat16 h = __builtin_bit_cast(__hip_bfloat16, s);
    return __bfloat162float(h);
}

// Pack Wc = [w1; wt] (320x320) into B-fragment order for mfma_f32_16x16x32_bf16.
// elem j of lane l for (t,kb): n = t*16+(l&15), k = kb*32+(l>>4)*8+j; flat (((t*10+kb)*64+l)*8+j)
__global__ void pack_wc(const float* __restrict__ w1, const float* __restrict__ wt,
                        unsigned short* __restrict__ dst) {
    int i = blockIdx.x * 256 + threadIdx.x;
    if (i >= 320 * 320) return;
    int j = i & 7;
    int lane = (i >> 3) & 63;
    int r = i >> 9;
    int kb = r % 10;
    int t = r / 10;
    int n = t * 16 + (lane & 15);
    int k = kb * 32 + ((lane >> 4) << 3) + j;
    float v = (n < 160) ? w1[n * 320 + k] : wt[(n - 160) * 320 + k];
    dst[i] = f2bf(v);
}

__global__ void pack_w2(const float* __restrict__ w2, unsigned short* __restrict__ dst) {
    int i = blockIdx.x * 256 + threadIdx.x;
    if (i >= 160 * 160) return;
    int j = i & 7;
    int lane = (i >> 3) & 63;
    int r = i >> 9;
    int kb = r % 5;
    int t = r / 5;
    int n = t * 16 + (lane & 15);
    int k = kb * 32 + ((lane >> 4) << 3) + j;
    dst[i] = f2bf(w2[n * 160 + k]);
}

__global__ __launch_bounds__(256, 3) void fused_kernel(
    const float* __restrict__ actors, const float* __restrict__ paths,
    const float* __restrict__ Z_act, const float* __restrict__ Z_pat,
    const int* __restrict__ u,
    const unsigned short* __restrict__ pB1, const unsigned short* __restrict__ pB2,
    const float* __restrict__ g1w, const float* __restrict__ g1b,
    const float* __restrict__ g2w, const float* __restrict__ g2b,
    const float* __restrict__ wh, const float* __restrict__ bh,
    float* __restrict__ out)
{
    // LDS map: [0,41984) lX (64 x XP bf16).  After GEMM1: [0,21504) lH1 (64 x HP bf16),
    // [21504,41984) lHT flat lane-major (2*4*5*4*64 shorts = 20480 B).  Stats at 41984.
    __shared__ __align__(16) char smem[43520];
    unsigned short* lX  = (unsigned short*)smem;
    unsigned short* lH1 = (unsigned short*)smem;
    unsigned short* lHT = (unsigned short*)(smem + 21504);
    float* sSum  = (float*)(smem + 41984);   // [2][64]
    float* sSq   = sSum + 128;               // [2][64]
    float* sMu   = sSum + 256;               // [64]
    float* sRstd = sSum + 320;               // [64]

    const int tid  = threadIdx.x;
    const int wave = tid >> 6;
    const int lane = tid & 63;
    const int quad = lane >> 4;
    const int l15  = lane & 15;
    const int row0 = blockIdx.x * 64;

    // ================= staging: phase-split for MLP =================
    // direct space: 64 rows x 40 quads (k 0..159); gather space: 64 x 40 (k 160..319)
    float4 vD[10], vG[10];
    int uv[10];
    #pragma unroll
    for (int i = 0; i < 10; i++) {          // phase A: direct loads + u loads
        int f = i * 256 + tid;
        int r = f / 40, q = f - r * 40;
        const float* src = (q < 32) ? (paths + (size_t)(row0 + r) * 128 + q * 4)
                                    : (Z_pat + (size_t)(row0 + r) * 32 + (q - 32) * 4);
        vD[i] = *(const float4*)src;
        uv[i] = u[row0 + r];
    }
    #pragma unroll
    for (int i = 0; i < 10; i++) {          // phase B: dependent gather loads
        int f = i * 256 + tid;
        int r = f / 40, q = f - r * 40;
        (void)r;
        int un = uv[i];
        const float* src = (q < 32) ? (actors + (size_t)un * 128 + q * 4)
                                    : (Z_act + (size_t)un * 32 + (q - 32) * 4);
        vG[i] = *(const float4*)src;
    }
    #pragma unroll
    for (int i = 0; i < 10; i++) {          // phase C: convert + LDS write
        int f = i * 256 + tid;
        int r = f / 40, q = f - r * 40;
        ushort4 sv;
        sv.x = f2bf(vD[i].x); sv.y = f2bf(vD[i].y); sv.z = f2bf(vD[i].z); sv.w = f2bf(vD[i].w);
        *(ushort4*)(lX + r * XP + q * 4) = sv;
    }
    #pragma unroll
    for (int i = 0; i < 10; i++) {
        int f = i * 256 + tid;
        int r = f / 40, q = f - r * 40;
        ushort4 sv;
        sv.x = f2bf(vG[i].x); sv.y = f2bf(vG[i].y); sv.z = f2bf(vG[i].z); sv.w = f2bf(vG[i].w);
        *(ushort4*)(lX + r * XP + 160 + q * 4) = sv;
    }

    // prefetch GEMM1 B fragments kb=0,1 (independent of LDS) before the barrier
    short8 bA[5], bB[5];
    #pragma unroll
    for (int ti = 0; ti < 5; ti++) {
        int t = wave * 5 + ti;
        bA[ti] = *(const short8*)(pB1 + ((size_t)(t * 10 + 0) * 64 + lane) * 8);
        bB[ti] = *(const short8*)(pB1 + ((size_t)(t * 10 + 1) * 64 + lane) * 8);
    }
    __syncthreads();

    // ================= GEMM1: C[64x320] = X @ [w1;wt]^T, n-split by wave =================
    floatx4 fzero = {0.f, 0.f, 0.f, 0.f};
    floatx4 acc[4][5];
    #pragma unroll
    for (int i = 0; i < 4; i++)
        #pragma unroll
        for (int j = 0; j < 5; j++) acc[i][j] = fzero;

    #pragma unroll
    for (int kb = 0; kb < 10; kb++) {
        short8 a[4];
        #pragma unroll
        for (int mt = 0; mt < 4; mt++)
            a[mt] = *(const short8*)(lX + (mt * 16 + l15) * XP + kb * 32 + quad * 8);
        short8 bN[5];
        if (kb + 2 < 10) {
            #pragma unroll
            for (int ti = 0; ti < 5; ti++) {
                int t = wave * 5 + ti;
                bN[ti] = *(const short8*)(pB1 + ((size_t)(t * 10 + kb + 2) * 64 + lane) * 8);
            }
        }
        #pragma unroll
        for (int ti = 0; ti < 5; ti++) {
            #pragma unroll
            for (int mt = 0; mt < 4; mt++)
                acc[mt][ti] = __builtin_amdgcn_mfma_f32_16x16x32_bf16(a[mt], bA[ti], acc[mt][ti], 0, 0, 0);
        }
        #pragma unroll
        for (int ti = 0; ti < 5; ti++) { bA[ti] = bB[ti]; bB[ti] = bN[ti]; }
    }
    __syncthreads();   // lX dead; safe to write lH1/lHT

    // ================= split: waves 2,3 write ht; waves 0,1 compute GN1 stats =================
    if (wave >= 2) {
        int wn = wave - 2;
        #pragma unroll
        for (int mtp = 0; mtp < 4; mtp++)
            #pragma unroll
            for (int ti = 0; ti < 5; ti++)
                #pragma unroll
                for (int r = 0; r < 4; r++)
                    lHT[((((wn * 4 + mtp) * 5 + ti) * 4 + r) << 6) + lane] = f2bf(acc[mtp][ti][r]);
    } else {
        float s[16], q2[16];
        #pragma unroll
        for (int mt = 0; mt < 4; mt++)
            #pragma unroll
            for (int r = 0; r < 4; r++) {
                float sv = 0.f, qv = 0.f;
                #pragma unroll
                for (int ti = 0; ti < 5; ti++) {
                    float v = acc[mt][ti][r];
                    sv += v; qv += v * v;
                }
                s[mt * 4 + r] = sv; q2[mt * 4 + r] = qv;
            }
        #pragma unroll
        for (int off = 1; off <= 8; off <<= 1)
            #pragma unroll
            for (int k = 0; k < 16; k++) {
                s[k]  += __shfl_xor(s[k],  off, 64);
                q2[k] += __shfl_xor(q2[k], off, 64);
            }
        if (l15 == 0) {
            #pragma unroll
            for (int mt = 0; mt < 4; mt++)
                #pragma unroll
                for (int r = 0; r < 4; r++) {
                    int m = mt * 16 + quad * 4 + r;
                    sSum[wave * 64 + m] = s[mt * 4 + r];
                    sSq[wave * 64 + m]  = q2[mt * 4 + r];
                }
        }
    }
    __syncthreads();

    if (tid < 64) {
        float ts = sSum[tid] + sSum[64 + tid];
        float tq = sSq[tid] + sSq[64 + tid];
        float mu = ts * (1.f / 160.f);
        float var = tq * (1.f / 160.f) - mu * mu;
        sMu[tid] = mu;
        sRstd[tid] = rsqrtf(var + 1e-5f);
    }
    __syncthreads();

    // ================= GN1 apply + ReLU + write h1 (waves 0,1) =================
    if (wave < 2) {
        float gw[5], gb[5];
        #pragma unroll
        for (int ti = 0; ti < 5; ti++) {
            int n = wave * 80 + ti * 16 + l15;
            gw[ti] = g1w[n]; gb[ti] = g1b[n];
        }
        #pragma unroll
        for (int mt = 0; mt < 4; mt++)
            #pragma unroll
            for (int r = 0; r < 4; r++) {
                int m = mt * 16 + quad * 4 + r;
                float mu = sMu[m], rs = sRstd[m];
                #pragma unroll
                for (int ti = 0; ti < 5; ti++) {
                    float v = (acc[mt][ti][r] - mu) * rs * gw[ti] + gb[ti];
                    v = fmaxf(v, 0.f);
                    lH1[m * HP + wave * 80 + ti * 16 + l15] = f2bf(v);
                }
            }
    }

    // prefetch GEMM2 B fragments kb=0,1
    const int wm = wave & 1, wn = wave >> 1;
    short8 b2A[5], b2B[5];
    #pragma unroll
    for (int ti = 0; ti < 5; ti++) {
        int t = wn * 5 + ti;
        b2A[ti] = *(const short8*)(pB2 + ((size_t)(t * 5 + 0) * 64 + lane) * 8);
        b2B[ti] = *(const short8*)(pB2 + ((size_t)(t * 5 + 1) * 64 + lane) * 8);
    }
    __syncthreads();

    // ================= GEMM2: h2[64x160] = h1 @ w2^T; (wm rows-half, wn cols-half) =================
    floatx4 acc2[2][5];
    #pragma unroll
    for (int i = 0; i < 2; i++)
        #pragma unroll
        for (int j = 0; j < 5; j++) acc2[i][j] = fzero;

    #pragma unroll
    for (int kb = 0; kb < 5; kb++) {
        short8 a[2];
        #pragma unroll
        for (int mt = 0; mt < 2; mt++)
            a[mt] = *(const short8*)(lH1 + (wm * 32 + mt * 16 + l15) * HP + kb * 32 + quad * 8);
        short8 bN[5];
        if (kb + 2 < 5) {
            #pragma unroll
            for (int ti = 0; ti < 5; ti++) {
                int t = wn * 5 + ti;
                bN[ti] = *(const short8*)(pB2 + ((size_t)(t * 5 + kb + 2) * 64 + lane) * 8);
            }
        }
        #pragma unroll
        for (int ti = 0; ti < 5; ti++) {
            #pragma unroll
            for (int mt = 0; mt < 2; mt++)
                acc2[mt][ti] = __builtin_amdgcn_mfma_f32_16x16x32_bf16(a[mt], b2A[ti], acc2[mt][ti], 0, 0, 0);
        }
        #pragma unroll
        for (int ti = 0; ti < 5; ti++) { b2A[ti] = b2B[ti]; b2B[ti] = bN[ti]; }
    }

    // ================= GN2 stats (in-register) =================
    {
        float s[8], q2[8];
        #pragma unroll
        for (int mt = 0; mt < 2; mt++)
            #pragma unroll
            for (int r = 0; r < 4; r++) {
                float sv = 0.f, qv = 0.f;
                #pragma unroll
                for (int ti = 0; ti < 5; ti++) {
                    float v = acc2[mt][ti][r];
                    sv += v; qv += v * v;
                }
                s[mt * 4 + r] = sv; q2[mt * 4 + r] = qv;
            }
        #pragma unroll
        for (int off = 1; off <= 8; off <<= 1)
            #pragma unroll
            for (int k = 0; k < 8; k++) {
                s[k]  += __shfl_xor(s[k],  off, 64);
                q2[k] += __shfl_xor(q2[k], off, 64);
            }
        if (l15 == 0) {
            #pragma unroll
            for (int mt = 0; mt < 2; mt++)
                #pragma unroll
                for (int r = 0; r < 4; r++) {
                    int m = wm * 32 + mt * 16 + quad * 4 + r;
                    sSum[wn * 64 + m] = s[mt * 4 + r];
                    sSq[wn * 64 + m]  = q2[mt * 4 + r];
                }
        }
    }
    __syncthreads();

    if (tid < 64) {
        float ts = sSum[tid] + sSum[64 + tid];
        float tq = sSq[tid] + sSq[64 + tid];
        float mu = ts * (1.f / 160.f);
        float var = tq * (1.f / 160.f) - mu * mu;
        sMu[tid] = mu;
        sRstd[tid] = rsqrtf(var + 1e-5f);
    }
    __syncthreads();

    // ================= GN2 apply + skip(ht) + ReLU + head dot =================
    {
        float g2wv[5], g2bv[5], whv[5];
        #pragma unroll
        for (int ti = 0; ti < 5; ti++) {
            int n = wn * 80 + ti * 16 + l15;
            g2wv[ti] = g2w[n]; g2bv[ti] = g2b[n]; whv[ti] = wh[n];
        }
        float dp[8];
        #pragma unroll
        for (int k = 0; k < 8; k++) dp[k] = 0.f;
        #pragma unroll
        for (int mt = 0; mt < 2; mt++)
            #pragma unroll
            for (int r = 0; r < 4; r++) {
                int m = wm * 32 + mt * 16 + quad * 4 + r;
                float mu = sMu[m], rs = sRstd[m];
                #pragma unroll
                for (int ti = 0; ti < 5; ti++) {
                    float v = (acc2[mt][ti][r] - mu) * rs * g2wv[ti] + g2bv[ti];
                    v += bf2f(lHT[((((wn * 4 + (wm * 2 + mt)) * 5 + ti) * 4 + r) << 6) + lane]);
                    v = fmaxf(v, 0.f);
                    dp[mt * 4 + r] += v * whv[ti];
                }
            }
        #pragma unroll
        for (int off = 1; off <= 8; off <<= 1)
            #pragma unroll
            for (int k = 0; k < 8; k++) dp[k] += __shfl_xor(dp[k], off, 64);
        __syncthreads();   // sMu/sRstd reads done before sSum reuse below
        if (l15 == 0) {
            #pragma unroll
            for (int mt = 0; mt < 2; mt++)
                #pragma unroll
                for (int r = 0; r < 4; r++) {
                    int m = wm * 32 + mt * 16 + quad * 4 + r;
                    sSum[wn * 64 + m] = dp[mt * 4 + r];
                }
        }
    }
    __syncthreads();
    if (tid < 64) out[row0 + tid] = sSum[tid] + sSum[64 + tid] + bh[0];
}

extern "C" void kernel_launch(void* const* d_in, const int* in_sizes, int n_in,
                              void* d_out, int out_size, void* d_ws, size_t ws_size,
                              hipStream_t stream) {
    const float* actors = (const float*)d_in[0];
    const float* paths  = (const float*)d_in[1];
    const float* Z_act  = (const float*)d_in[2];
    const float* Z_pat  = (const float*)d_in[3];
    const int*   u      = (const int*)d_in[4];
    const float* w1     = (const float*)d_in[5];
    const float* w2     = (const float*)d_in[6];
    const float* wt     = (const float*)d_in[7];
    const float* g1w    = (const float*)d_in[8];
    const float* g1b    = (const float*)d_in[9];
    const float* g2w    = (const float*)d_in[10];
    const float* g2b    = (const float*)d_in[11];
    const float* wh     = (const float*)d_in[12];
    const float* bh     = (const float*)d_in[13];
    float* out = (float*)d_out;

    unsigned short* pB1 = (unsigned short*)d_ws;
    unsigned short* pB2 = pB1 + 320 * 320;

    hipLaunchKernelGGL(pack_wc, dim3(400), dim3(256), 0, stream, w1, wt, pB1);
    hipLaunchKernelGGL(pack_w2, dim3(100), dim3(256), 0, stream, w2, pB2);
    hipLaunchKernelGGL(fused_kernel, dim3(400000 / 64), dim3(256), 0, stream,
                       actors, paths, Z_act, Z_pat, u, pB1, pB2,
                       g1w, g1b, g2w, g2b, wh, bh, out);
}